// Round 6
// baseline (269.969 us; speedup 1.0000x reference)
//
#include <hip/hip_runtime.h>
#include <math.h>

#define NEG_V (-1e30f)
#define SLOPE_V 0.01f
#define EPS_V 1e-5f

typedef __attribute__((ext_vector_type(8))) short bs8;    // 8 bf16 (4 VGPRs)
typedef __attribute__((ext_vector_type(4))) float f32x4;  // mfma acc

// Split fp32 x into bf16 hi + bf16 lo (RNE both). x ≈ hi + lo, rel err ~2^-17.
__device__ __forceinline__ void split2(float x, unsigned short& hi, unsigned short& lo) {
    unsigned u = __float_as_uint(x);
    unsigned h = (u + 0x7FFFu + ((u >> 16) & 1u)) >> 16;
    hi = (unsigned short)h;
    float hf = __uint_as_float(h << 16);
    float l = x - hf;
    unsigned ul = __float_as_uint(l);
    lo = (unsigned short)((ul + 0x7FFFu + ((ul >> 16) & 1u)) >> 16);
}

// ---------------------------------------------------------------------------
// Pure-bf16 split MFMA mainloop (validated round 4). Block = 256 thr
// (4 waves), tile 64x64, wave tile 32x32, 3 mfma per tile (hh, hl, lh).
// A pre-split row-major [M][K]; B pre-split transposed Bt[n][k].
// LDS rows padded to 40 bf16 (80 B).
// ---------------------------------------------------------------------------
__device__ __forceinline__ void mfma_loop(
    const unsigned short* __restrict__ Ahg, const unsigned short* __restrict__ Alg,
    int lda,
    const unsigned short* __restrict__ Bhg, const unsigned short* __restrict__ Blg,
    int ldb, int K, int row0, int col0,
    f32x4 (&acc)[2][2],
    unsigned short (*Ah)[40], unsigned short (*Al)[40],
    unsigned short (*Bh)[40], unsigned short (*Bl)[40])
{
    const int tid = threadIdx.x;
    const int lane = tid & 63, wid = tid >> 6;
    const int wm0 = (wid >> 1) * 32, wn0 = (wid & 1) * 32;
    const int lm = lane & 15, q = lane >> 4;
    const int sr = tid >> 2, sc = (tid & 3) * 8;

    for (int k0 = 0; k0 < K; k0 += 32) {
        *(bs8*)&Ah[sr][sc] = *(const bs8*)(Ahg + (size_t)(row0 + sr) * lda + k0 + sc);
        *(bs8*)&Al[sr][sc] = *(const bs8*)(Alg + (size_t)(row0 + sr) * lda + k0 + sc);
        *(bs8*)&Bh[sr][sc] = *(const bs8*)(Bhg + (size_t)(col0 + sr) * ldb + k0 + sc);
        *(bs8*)&Bl[sr][sc] = *(const bs8*)(Blg + (size_t)(col0 + sr) * ldb + k0 + sc);
        __syncthreads();

        bs8 a_h[2], a_l[2], b_h[2], b_l[2];
#pragma unroll
        for (int t = 0; t < 2; t++) {
            a_h[t] = *(bs8*)&Ah[wm0 + t * 16 + lm][q * 8];
            a_l[t] = *(bs8*)&Al[wm0 + t * 16 + lm][q * 8];
            b_h[t] = *(bs8*)&Bh[wn0 + t * 16 + lm][q * 8];
            b_l[t] = *(bs8*)&Bl[wn0 + t * 16 + lm][q * 8];
        }
#pragma unroll
        for (int mt = 0; mt < 2; mt++)
#pragma unroll
            for (int nt = 0; nt < 2; nt++) {
                acc[mt][nt] = __builtin_amdgcn_mfma_f32_16x16x32_bf16(a_h[mt], b_h[nt], acc[mt][nt], 0, 0, 0);
                acc[mt][nt] = __builtin_amdgcn_mfma_f32_16x16x32_bf16(a_h[mt], b_l[nt], acc[mt][nt], 0, 0, 0);
                acc[mt][nt] = __builtin_amdgcn_mfma_f32_16x16x32_bf16(a_l[mt], b_h[nt], acc[mt][nt], 0, 0, 0);
            }
        __syncthreads();
    }
}

// 64x64 fp32 tile -> transposed bf16 hi/lo (dst[n][k] = src[k][n]).
__device__ __forceinline__ void transpose_split_tile(
    const float* __restrict__ src, int src_ld,
    unsigned short* __restrict__ dh, unsigned short* __restrict__ dl, int dst_ld,
    unsigned short (*Th)[72], unsigned short (*Tl)[72])
{
    int tid = threadIdx.x;
    int r = tid >> 2;
    int cb = (tid & 3) * 16;
#pragma unroll
    for (int cc = 0; cc < 16; cc += 4) {
        float4 v = *(const float4*)(src + (size_t)r * src_ld + cb + cc);
        unsigned short hh, ll;
        split2(v.x, hh, ll); Th[cb + cc + 0][r] = hh; Tl[cb + cc + 0][r] = ll;
        split2(v.y, hh, ll); Th[cb + cc + 1][r] = hh; Tl[cb + cc + 1][r] = ll;
        split2(v.z, hh, ll); Th[cb + cc + 2][r] = hh; Tl[cb + cc + 2][r] = ll;
        split2(v.w, hh, ll); Th[cb + cc + 3][r] = hh; Tl[cb + cc + 3][r] = ll;
    }
    __syncthreads();
    int n = tid >> 2, ch = (tid & 3) * 8;
    *(bs8*)(dh + (size_t)n * dst_ld + ch)      = *(bs8*)&Th[n][ch];
    *(bs8*)(dh + (size_t)n * dst_ld + ch + 32) = *(bs8*)&Th[n][ch + 32];
    *(bs8*)(dl + (size_t)n * dst_ld + ch)      = *(bs8*)&Tl[n][ch];
    *(bs8*)(dl + (size_t)n * dst_ld + ch + 32) = *(bs8*)&Tl[n][ch + 32];
}

// ---------------------------------------------------------------------------
// Prep: W0,W1 -> Wt (transposed split); A1 -> A1t (transposed split);
// feature -> fh/fl (row-major split). grid 504.
// ---------------------------------------------------------------------------
__global__ __launch_bounds__(256) void prep_k(
    const float* __restrict__ W0, const float* __restrict__ W1,
    const float* __restrict__ A1, const float* __restrict__ feature,
    unsigned short* Wt0h, unsigned short* Wt0l,
    unsigned short* Wt1h, unsigned short* Wt1l,
    unsigned short* A1th, unsigned short* A1tl,
    unsigned short* fh, unsigned short* fl)
{
    __shared__ unsigned short Th[64][72], Tl[64][72];
    int id = blockIdx.x;
    if (id < 144) {
        int kt = id / 12, nt = id % 12;
        transpose_split_tile(W0 + (size_t)(kt * 64) * 768 + nt * 64, 768,
                             Wt0h + (size_t)(nt * 64) * 768 + kt * 64,
                             Wt0l + (size_t)(nt * 64) * 768 + kt * 64, 768, Th, Tl);
    } else if (id < 288) {
        int r = id - 144, kt = r / 12, nt = r % 12;
        transpose_split_tile(W1 + (size_t)(kt * 64) * 768 + nt * 64, 768,
                             Wt1h + (size_t)(nt * 64) * 768 + kt * 64,
                             Wt1l + (size_t)(nt * 64) * 768 + kt * 64, 768, Th, Tl);
    } else if (id < 312) {
        int r = id - 288, kt = r >> 1, nh = r & 1;
        transpose_split_tile(A1 + (size_t)(nh * 768 + kt * 64) * 64, 64,
                             A1th + (size_t)(nh * 64) * 768 + kt * 64,
                             A1tl + (size_t)(nh * 64) * 768 + kt * 64, 768, Th, Tl);
    } else {
        // feature split: 192 blocks x 4096 elems, 16 per thread
        size_t base = (size_t)(id - 312) * 4096 + threadIdx.x * 16;
        unsigned short hh, ll;
#pragma unroll
        for (int g = 0; g < 2; g++) {
            bs8 sh, sl;
#pragma unroll
            for (int cc = 0; cc < 8; cc += 4) {
                float4 v = *(const float4*)(feature + base + g * 8 + cc);
                split2(v.x, hh, ll); sh[cc + 0] = (short)hh; sl[cc + 0] = (short)ll;
                split2(v.y, hh, ll); sh[cc + 1] = (short)hh; sl[cc + 1] = (short)ll;
                split2(v.z, hh, ll); sh[cc + 2] = (short)hh; sl[cc + 2] = (short)ll;
                split2(v.w, hh, ll); sh[cc + 3] = (short)hh; sl[cc + 3] = (short)ll;
            }
            *(bs8*)(fh + base + g * 8) = sh;
            *(bs8*)(fl + base + g * 8) = sl;
        }
    }
}

// ---------------------------------------------------------------------------
// h = A @ W + bias; outputs SPLIT row-major (hh/hl) and SPLIT TRANSPOSED
// per-batch (hth/htl). grid (12,16). (validated round 4)
// ---------------------------------------------------------------------------
__global__ __launch_bounds__(256) void gemm_mfma_bias_k(
    const unsigned short* __restrict__ Ahg, const unsigned short* __restrict__ Alg,
    const unsigned short* __restrict__ Bth, const unsigned short* __restrict__ Btl,
    const float* __restrict__ bias,
    unsigned short* __restrict__ hh, unsigned short* __restrict__ hl,
    unsigned short* __restrict__ hth, unsigned short* __restrict__ htl)
{
    __shared__ unsigned short smem[4][64][40];   // 10240 shorts
    int row0 = blockIdx.y * 64, col0 = blockIdx.x * 64;
    f32x4 acc[2][2] = {};
    mfma_loop(Ahg, Alg, 768, Bth, Btl, 768, 768, row0, col0, acc,
              smem[0], smem[1], smem[2], smem[3]);
    __syncthreads();
    unsigned short* flat = &smem[0][0][0];
    unsigned short (*Hi)[69] = (unsigned short(*)[69])flat;            // 4416 shorts
    unsigned short (*Lo)[69] = (unsigned short(*)[69])(flat + 4416);   // 8832 <= 10240
    int tid = threadIdx.x, lane = tid & 63, wid = tid >> 6;
    int wm0 = (wid >> 1) * 32, wn0 = (wid & 1) * 32;
    int lm = lane & 15, q = lane >> 4;
#pragma unroll
    for (int mt = 0; mt < 2; mt++)
#pragma unroll
        for (int nt = 0; nt < 2; nt++) {
            int c = wn0 + nt * 16 + lm;
            float bv = bias[col0 + c];
#pragma unroll
            for (int i = 0; i < 4; i++) {
                int r = wm0 + mt * 16 + q * 4 + i;
                unsigned short hv, lv;
                split2(acc[mt][nt][i] + bv, hv, lv);
                Hi[r][c] = hv; Lo[r][c] = lv;
            }
        }
    __syncthreads();
    {   // row-major split out
        int r = tid >> 2, cq = (tid & 3) * 16;
        bs8 vh0, vh1, vl0, vl1;
#pragma unroll
        for (int e = 0; e < 8; e++) {
            vh0[e] = Hi[r][cq + e];     vh1[e] = Hi[r][cq + 8 + e];
            vl0[e] = Lo[r][cq + e];     vl1[e] = Lo[r][cq + 8 + e];
        }
        size_t ro = (size_t)(row0 + r) * 768 + col0 + cq;
        *(bs8*)(hh + ro) = vh0; *(bs8*)(hh + ro + 8) = vh1;
        *(bs8*)(hl + ro) = vl0; *(bs8*)(hl + ro + 8) = vl1;
    }
    {   // transposed split out: hth[b][d][k], ld 128
        int d = tid >> 2, kq = (tid & 3) * 16;
        int b = row0 >> 7, kb = row0 & 127;
        bs8 th0, th1, tl0, tl1;
#pragma unroll
        for (int e = 0; e < 8; e++) {
            th0[e] = Hi[kq + e][d];     th1[e] = Hi[kq + 8 + e][d];
            tl0[e] = Lo[kq + e][d];     tl1[e] = Lo[kq + 8 + e][d];
        }
        size_t to = ((size_t)b * 768 + col0 + d) * 128 + kb + kq;
        *(bs8*)(hth + to) = th0; *(bs8*)(hth + to + 8) = th1;
        *(bs8*)(htl + to) = tl0; *(bs8*)(htl + to + 8) = tl1;
    }
}

// ---------------------------------------------------------------------------
// sproj split-K: s_part[kc] = h[:, kc*384:+384] @ A1t chunk. grid (2,16,2).
// Partials summed inside mid_k. (validated round 4)
// ---------------------------------------------------------------------------
__global__ __launch_bounds__(256) void sproj_mfma_k(
    const unsigned short* __restrict__ hh, const unsigned short* __restrict__ hl,
    const unsigned short* __restrict__ A1th, const unsigned short* __restrict__ A1tl,
    float* __restrict__ s)
{
    __shared__ unsigned short smem[4][64][40];
    int col0 = blockIdx.x * 64, row0 = blockIdx.y * 64, kc = blockIdx.z;
    f32x4 acc[2][2] = {};
    mfma_loop(hh + kc * 384, hl + kc * 384, 768,
              A1th + kc * 384, A1tl + kc * 384, 768,
              384, row0, col0, acc, smem[0], smem[1], smem[2], smem[3]);
    float* sp = s + (size_t)kc * 131072;
    int lane = threadIdx.x & 63, wid = threadIdx.x >> 6;
    int wm0 = (wid >> 1) * 32, wn0 = (wid & 1) * 32;
    int lm = lane & 15, q = lane >> 4;
#pragma unroll
    for (int mt = 0; mt < 2; mt++)
#pragma unroll
        for (int nt = 0; nt < 2; nt++) {
            int c = col0 + wn0 + nt * 16 + lm;
#pragma unroll
            for (int i = 0; i < 4; i++) {
                int r = row0 + wm0 + mt * 16 + q * 4 + i;
                sp[(size_t)r * 128 + c] = acc[mt][nt][i];
            }
        }
}

// ---------------------------------------------------------------------------
// mid_k: fused score + flattened softmax for one batch. grid 8, block 256.
// Scores live in 64 VGPRs/thread (ev[8][2][4]); writes split exp to ph/pl
// and the sum to stats (1/sum applied in attn epilogue).
// ---------------------------------------------------------------------------
__global__ __launch_bounds__(256) void mid_k(
    const float* __restrict__ s, const int* __restrict__ adj,
    const float* __restrict__ ab1, const float* __restrict__ A2,
    const float* __restrict__ ab2,
    unsigned short* __restrict__ ph, unsigned short* __restrict__ pl,
    float* __restrict__ stats)
{
    __shared__ float st[128][65];
    __shared__ float ss[16][65];
    __shared__ float a2s[64], ab1s[64];
    __shared__ float red[256];
    const int b = blockIdx.x, tid = threadIdx.x;
    for (int idx = tid; idx < 8192; idx += 256) {
        int j = idx >> 6, h2 = idx & 63;
        size_t off = (size_t)(b * 128 + j) * 128 + 64 + h2;
        st[j][h2] = s[off] + s[off + 131072];
    }
    if (tid < 64) { a2s[tid] = A2[tid]; ab1s[tid] = ab1[tid]; }
    __syncthreads();
    const float ab2v = ab2[0];
    const int it = tid >> 5, jt = tid & 31;
    float ev[8][2][4];
    float mx = -3.4e38f;
#pragma unroll
    for (int pass = 0; pass < 8; pass++) {
        const int i0 = pass * 16;
        for (int idx = tid; idx < 1024; idx += 256) {
            int i = idx >> 6, h2 = idx & 63;
            size_t off = (size_t)(b * 128 + i0 + i) * 128 + h2;
            ss[i][h2] = s[off] + s[off + 131072] + ab1s[h2];
        }
        __syncthreads();
        float a0acc[4] = {}, a1acc[4] = {};
        for (int h2 = 0; h2 < 64; h2++) {
            float a0 = ss[it * 2 + 0][h2];
            float a1 = ss[it * 2 + 1][h2];
            float cv = a2s[h2];
#pragma unroll
            for (int e = 0; e < 4; e++) {
                float bb = st[jt + 32 * e][h2];
                a0acc[e] = fmaf(fmaxf(a0 + bb, 0.f), cv, a0acc[e]);
                a1acc[e] = fmaf(fmaxf(a1 + bb, 0.f), cv, a1acc[e]);
            }
        }
#pragma unroll
        for (int e = 0; e < 4; e++) {
            int ig = i0 + it * 2, jg = jt + 32 * e;
            float e0 = a0acc[e] + ab2v, e1 = a1acc[e] + ab2v;
            e0 = (e0 > 0.f) ? e0 : SLOPE_V * e0;
            e1 = (e1 > 0.f) ? e1 : SLOPE_V * e1;
            int ad0 = adj[(size_t)b * 16384 + (size_t)ig * 128 + jg];
            int ad1 = adj[(size_t)b * 16384 + (size_t)(ig + 1) * 128 + jg];
            ev[pass][0][e] = ad0 ? e0 : NEG_V;
            ev[pass][1][e] = ad1 ? e1 : NEG_V;
            mx = fmaxf(mx, fmaxf(ev[pass][0][e], ev[pass][1][e]));
        }
        __syncthreads();
    }
    red[tid] = mx;
    __syncthreads();
    for (int sft = 128; sft > 0; sft >>= 1) {
        if (tid < sft) red[tid] = fmaxf(red[tid], red[tid + sft]);
        __syncthreads();
    }
    const float M = red[0];
    __syncthreads();
    float sum = 0.f;
#pragma unroll
    for (int pass = 0; pass < 8; pass++)
#pragma unroll
        for (int ii = 0; ii < 2; ii++)
#pragma unroll
            for (int e = 0; e < 4; e++) {
                float v = expf(ev[pass][ii][e] - M);
                sum += v;
                unsigned short hv, lv;
                split2(v, hv, lv);
                size_t off = (size_t)b * 16384 +
                             (size_t)(pass * 16 + it * 2 + ii) * 128 + jt + 32 * e;
                ph[off] = hv;
                pl[off] = lv;
            }
    red[tid] = sum;
    __syncthreads();
    for (int sft = 128; sft > 0; sft >>= 1) {
        if (tid < sft) red[tid] += red[tid + sft];
        __syncthreads();
    }
    if (tid == 0) stats[b] = red[0];
}

// ---------------------------------------------------------------------------
// node[b] = (1/sum_b) * P[b] @ h[b]; outputs fp32 node AND split nodeh/nodel.
// grid (12,2,8). (validated round 4)
// ---------------------------------------------------------------------------
__global__ __launch_bounds__(256) void attn_mfma_k(
    const unsigned short* __restrict__ ph, const unsigned short* __restrict__ pl,
    const unsigned short* __restrict__ hth, const unsigned short* __restrict__ htl,
    const float* __restrict__ stats, float* __restrict__ node,
    unsigned short* __restrict__ nodeh, unsigned short* __restrict__ nodel)
{
    __shared__ unsigned short smem[4][64][40];
    int b = blockIdx.z;
    int row0 = blockIdx.y * 64, col0 = blockIdx.x * 64;
    f32x4 acc[2][2] = {};
    mfma_loop(ph + (size_t)b * 16384, pl + (size_t)b * 16384, 128,
              hth + (size_t)b * 98304, htl + (size_t)b * 98304, 128, 128,
              row0, col0, acc, smem[0], smem[1], smem[2], smem[3]);
    __syncthreads();
    float alpha = 1.0f / stats[b];
    float* C = node + (size_t)b * 98304;
    unsigned short* flat = &smem[0][0][0];
    unsigned short (*Hi)[69] = (unsigned short(*)[69])flat;
    unsigned short (*Lo)[69] = (unsigned short(*)[69])(flat + 4416);
    int tid = threadIdx.x, lane = tid & 63, wid = tid >> 6;
    int wm0 = (wid >> 1) * 32, wn0 = (wid & 1) * 32;
    int lm = lane & 15, q = lane >> 4;
#pragma unroll
    for (int mt = 0; mt < 2; mt++)
#pragma unroll
        for (int nt = 0; nt < 2; nt++) {
            int c = wn0 + nt * 16 + lm;
#pragma unroll
            for (int i = 0; i < 4; i++) {
                int r = wm0 + mt * 16 + q * 4 + i;
                float v = acc[mt][nt][i] * alpha;
                C[(size_t)(row0 + r) * 768 + col0 + c] = v;
                unsigned short hv, lv;
                split2(v, hv, lv);
                Hi[r][c] = hv; Lo[r][c] = lv;
            }
        }
    __syncthreads();
    int r = tid >> 2, cq = (tid & 3) * 16;
    bs8 vh0, vh1, vl0, vl1;
#pragma unroll
    for (int e = 0; e < 8; e++) {
        vh0[e] = Hi[r][cq + e];     vh1[e] = Hi[r][cq + 8 + e];
        vl0[e] = Lo[r][cq + e];     vl1[e] = Lo[r][cq + 8 + e];
    }
    size_t ro = (size_t)(b * 128 + row0 + r) * 768 + col0 + cq;
    *(bs8*)(nodeh + ro) = vh0; *(bs8*)(nodeh + ro + 8) = vh1;
    *(bs8*)(nodel + ro) = vl0; *(bs8*)(nodel + ro + 8) = vl1;
}

// ---------------------------------------------------------------------------
// Fused graph-sum + batch-norm. grid 12, block 512.
// ---------------------------------------------------------------------------
__global__ __launch_bounds__(512) void gsum_bnorm_k(
    const float* __restrict__ node, const float* __restrict__ gamma,
    const float* __restrict__ beta, float* __restrict__ out)
{
    __shared__ float gbuf[8][64];
    __shared__ float mean_s[64], inv_s[64];
    int tid = threadIdx.x;
    int bg = tid >> 6, dl = tid & 63;
    int d = blockIdx.x * 64 + dl;
    float v = 0.f;
    for (int i = 0; i < 128; i++)
        v += node[(size_t)(bg * 128 + i) * 768 + d];
    gbuf[bg][dl] = v;
    __syncthreads();
    if (tid < 64) {
        float m = 0.f;
#pragma unroll
        for (int b = 0; b < 8; b++) m += gbuf[b][tid];
        m *= 0.125f;
        float var = 0.f;
#pragma unroll
        for (int b = 0; b < 8; b++) { float t = gbuf[b][tid] - m; var += t * t; }
        var *= 0.125f;
        mean_s[tid] = m;
        inv_s[tid] = 1.0f / sqrtf(var + EPS_V);
    }
    __syncthreads();
    out[bg * 768 + d] = gamma[d] * (v - mean_s[dl]) * inv_s[dl] + beta[d];
}

// ---------------------------------------------------------------------------
extern "C" void kernel_launch(void* const* d_in, const int* in_sizes, int n_in,
                              void* d_out, int out_size, void* d_ws, size_t ws_size,
                              hipStream_t stream)
{
    const float* feature = (const float*)d_in[0];
    // d_in[1] = aspect: unused by the reference
    const int*   adj     = (const int*)d_in[2];
    const float* W0      = (const float*)d_in[3];
    const float* b0      = (const float*)d_in[4];
    const float* W1      = (const float*)d_in[5];
    const float* b1      = (const float*)d_in[6];
    const float* A1      = (const float*)d_in[7];
    const float* ab1     = (const float*)d_in[8];
    const float* A2      = (const float*)d_in[9];
    const float* ab2     = (const float*)d_in[10];
    const float* gamma   = (const float*)d_in[11];
    const float* beta    = (const float*)d_in[12];

    float* ws    = (float*)d_ws;
    float* s     = ws;               // 2 x 131072 (split-K partials)
    float* stats = ws + 262144;      // 16
    unsigned short* u = (unsigned short*)(ws + 262160);  // 16B-aligned
    unsigned short* Wt0h = u;                   // 589824 each
    unsigned short* Wt0l = Wt0h + 589824;
    unsigned short* Wt1h = Wt0l + 589824;
    unsigned short* Wt1l = Wt1h + 589824;
    unsigned short* A1th = Wt1l + 589824;       // 98304 each
    unsigned short* A1tl = A1th + 98304;
    unsigned short* fh   = A1tl + 98304;        // 786432 each from here
    unsigned short* fl   = fh + 786432;
    unsigned short* hh   = fl + 786432;
    unsigned short* hl   = hh + 786432;
    unsigned short* hth  = hl + 786432;
    unsigned short* htl  = hth + 786432;
    unsigned short* ndh  = htl + 786432;
    unsigned short* ndl  = ndh + 786432;
    unsigned short* ph   = ndl + 786432;        // 131072 each
    unsigned short* pl   = ph + 131072;

    float* out       = (float*)d_out;
    float* graph_out = out;          // (8,768)
    float* node_out  = out + 6144;   // (8,128,768)

    prep_k<<<504, 256, 0, stream>>>(W0, W1, A1, feature,
                                    Wt0h, Wt0l, Wt1h, Wt1l, A1th, A1tl, fh, fl);

    for (int layer = 0; layer < 2; layer++) {
        const unsigned short* Wth = layer ? Wt1h : Wt0h;
        const unsigned short* Wtl = layer ? Wt1l : Wt0l;
        const float* bb = layer ? b1 : b0;
        const unsigned short* Ahg = layer ? ndh : fh;
        const unsigned short* Alg = layer ? ndl : fl;
        gemm_mfma_bias_k<<<dim3(12, 16), 256, 0, stream>>>(Ahg, Alg, Wth, Wtl, bb,
                                                           hh, hl, hth, htl);
        sproj_mfma_k<<<dim3(2, 16, 2), 256, 0, stream>>>(hh, hl, A1th, A1tl, s);
        mid_k<<<8, 256, 0, stream>>>(s, adj, ab1, A2, ab2, ph, pl, stats);
        attn_mfma_k<<<dim3(12, 2, 8), 256, 0, stream>>>(ph, pl, hth, htl, stats,
                                                        node_out, ndh, ndl);
    }
    gsum_bnorm_k<<<12, 512, 0, stream>>>(node_out, gamma, beta, graph_out);
}

// Round 7
// 192.557 us; speedup vs baseline: 1.4020x; 1.4020x over previous
//
#include <hip/hip_runtime.h>
#include <math.h>

#define NEG_V (-1e30f)
#define SLOPE_V 0.01f
#define EPS_V 1e-5f

typedef __attribute__((ext_vector_type(8))) short bs8;    // 8 bf16 (4 VGPRs)
typedef __attribute__((ext_vector_type(4))) float f32x4;  // mfma acc

// Split fp32 x into bf16 hi + bf16 lo (RNE both). x ≈ hi + lo, rel err ~2^-17.
__device__ __forceinline__ void split2(float x, unsigned short& hi, unsigned short& lo) {
    unsigned u = __float_as_uint(x);
    unsigned h = (u + 0x7FFFu + ((u >> 16) & 1u)) >> 16;
    hi = (unsigned short)h;
    float hf = __uint_as_float(h << 16);
    float l = x - hf;
    unsigned ul = __float_as_uint(l);
    lo = (unsigned short)((ul + 0x7FFFu + ((ul >> 16) & 1u)) >> 16);
}

// ---------------------------------------------------------------------------
// Pure-bf16 split MFMA mainloop (validated rounds 4/6). 256 thr, tile 64x64,
// wave tile 32x32, 3 mfma per tile (hh, hl, lh). A row-major split [M][K];
// B transposed split Bt[n][k]. LDS rows padded to 40 bf16.
// ---------------------------------------------------------------------------
__device__ __forceinline__ void mfma_loop(
    const unsigned short* __restrict__ Ahg, const unsigned short* __restrict__ Alg,
    int lda,
    const unsigned short* __restrict__ Bhg, const unsigned short* __restrict__ Blg,
    int ldb, int K, int row0, int col0,
    f32x4 (&acc)[2][2],
    unsigned short (*Ah)[40], unsigned short (*Al)[40],
    unsigned short (*Bh)[40], unsigned short (*Bl)[40])
{
    const int tid = threadIdx.x;
    const int lane = tid & 63, wid = tid >> 6;
    const int wm0 = (wid >> 1) * 32, wn0 = (wid & 1) * 32;
    const int lm = lane & 15, q = lane >> 4;
    const int sr = tid >> 2, sc = (tid & 3) * 8;

    for (int k0 = 0; k0 < K; k0 += 32) {
        *(bs8*)&Ah[sr][sc] = *(const bs8*)(Ahg + (size_t)(row0 + sr) * lda + k0 + sc);
        *(bs8*)&Al[sr][sc] = *(const bs8*)(Alg + (size_t)(row0 + sr) * lda + k0 + sc);
        *(bs8*)&Bh[sr][sc] = *(const bs8*)(Bhg + (size_t)(col0 + sr) * ldb + k0 + sc);
        *(bs8*)&Bl[sr][sc] = *(const bs8*)(Blg + (size_t)(col0 + sr) * ldb + k0 + sc);
        __syncthreads();

        bs8 a_h[2], a_l[2], b_h[2], b_l[2];
#pragma unroll
        for (int t = 0; t < 2; t++) {
            a_h[t] = *(bs8*)&Ah[wm0 + t * 16 + lm][q * 8];
            a_l[t] = *(bs8*)&Al[wm0 + t * 16 + lm][q * 8];
            b_h[t] = *(bs8*)&Bh[wn0 + t * 16 + lm][q * 8];
            b_l[t] = *(bs8*)&Bl[wn0 + t * 16 + lm][q * 8];
        }
#pragma unroll
        for (int mt = 0; mt < 2; mt++)
#pragma unroll
            for (int nt = 0; nt < 2; nt++) {
                acc[mt][nt] = __builtin_amdgcn_mfma_f32_16x16x32_bf16(a_h[mt], b_h[nt], acc[mt][nt], 0, 0, 0);
                acc[mt][nt] = __builtin_amdgcn_mfma_f32_16x16x32_bf16(a_h[mt], b_l[nt], acc[mt][nt], 0, 0, 0);
                acc[mt][nt] = __builtin_amdgcn_mfma_f32_16x16x32_bf16(a_l[mt], b_h[nt], acc[mt][nt], 0, 0, 0);
            }
        __syncthreads();
    }
}

// 64x64 fp32 tile -> transposed bf16 hi/lo (dst[n][k] = src[k][n]).
__device__ __forceinline__ void transpose_split_tile(
    const float* __restrict__ src, int src_ld,
    unsigned short* __restrict__ dh, unsigned short* __restrict__ dl, int dst_ld,
    unsigned short (*Th)[72], unsigned short (*Tl)[72])
{
    int tid = threadIdx.x;
    int r = tid >> 2;
    int cb = (tid & 3) * 16;
#pragma unroll
    for (int cc = 0; cc < 16; cc += 4) {
        float4 v = *(const float4*)(src + (size_t)r * src_ld + cb + cc);
        unsigned short hh, ll;
        split2(v.x, hh, ll); Th[cb + cc + 0][r] = hh; Tl[cb + cc + 0][r] = ll;
        split2(v.y, hh, ll); Th[cb + cc + 1][r] = hh; Tl[cb + cc + 1][r] = ll;
        split2(v.z, hh, ll); Th[cb + cc + 2][r] = hh; Tl[cb + cc + 2][r] = ll;
        split2(v.w, hh, ll); Th[cb + cc + 3][r] = hh; Tl[cb + cc + 3][r] = ll;
    }
    __syncthreads();
    int n = tid >> 2, ch = (tid & 3) * 8;
    *(bs8*)(dh + (size_t)n * dst_ld + ch)      = *(bs8*)&Th[n][ch];
    *(bs8*)(dh + (size_t)n * dst_ld + ch + 32) = *(bs8*)&Th[n][ch + 32];
    *(bs8*)(dl + (size_t)n * dst_ld + ch)      = *(bs8*)&Tl[n][ch];
    *(bs8*)(dl + (size_t)n * dst_ld + ch + 32) = *(bs8*)&Tl[n][ch + 32];
}

// flat fp32 -> split bf16 hi/lo, 4096 elems/block, 16/thread.
__device__ __forceinline__ void flat_split_job(
    const float* __restrict__ src, unsigned short* __restrict__ dh,
    unsigned short* __restrict__ dl, size_t base)
{
    unsigned short hh, ll;
#pragma unroll
    for (int g = 0; g < 2; g++) {
        bs8 sh, sl;
#pragma unroll
        for (int cc = 0; cc < 8; cc += 4) {
            float4 v = *(const float4*)(src + base + g * 8 + cc);
            split2(v.x, hh, ll); sh[cc + 0] = (short)hh; sl[cc + 0] = (short)ll;
            split2(v.y, hh, ll); sh[cc + 1] = (short)hh; sl[cc + 1] = (short)ll;
            split2(v.z, hh, ll); sh[cc + 2] = (short)hh; sl[cc + 2] = (short)ll;
            split2(v.w, hh, ll); sh[cc + 3] = (short)hh; sl[cc + 3] = (short)ll;
        }
        *(bs8*)(dh + base + g * 8) = sh;
        *(bs8*)(dl + base + g * 8) = sl;
    }
}

// ---------------------------------------------------------------------------
// Prep, grid 794: Wt (transposed split), A1t (transposed split), feature
// split, W row-major split (for wa_gemm B), bA = b @ A1 (2 layers).
// ---------------------------------------------------------------------------
__global__ __launch_bounds__(256) void prep_k(
    const float* __restrict__ W0, const float* __restrict__ W1,
    const float* __restrict__ A1, const float* __restrict__ feature,
    const float* __restrict__ b0, const float* __restrict__ b1,
    unsigned short* Wt0h, unsigned short* Wt0l,
    unsigned short* Wt1h, unsigned short* Wt1l,
    unsigned short* A1th, unsigned short* A1tl,
    unsigned short* fh, unsigned short* fl,
    unsigned short* Wrm0h, unsigned short* Wrm0l,
    unsigned short* Wrm1h, unsigned short* Wrm1l,
    float* bA)
{
    __shared__ unsigned short Th[64][72], Tl[64][72];
    __shared__ float redb[256];
    int id = blockIdx.x, tid = threadIdx.x;
    if (id < 144) {
        int kt = id / 12, nt = id % 12;
        transpose_split_tile(W0 + (size_t)(kt * 64) * 768 + nt * 64, 768,
                             Wt0h + (size_t)(nt * 64) * 768 + kt * 64,
                             Wt0l + (size_t)(nt * 64) * 768 + kt * 64, 768, Th, Tl);
    } else if (id < 288) {
        int r = id - 144, kt = r / 12, nt = r % 12;
        transpose_split_tile(W1 + (size_t)(kt * 64) * 768 + nt * 64, 768,
                             Wt1h + (size_t)(nt * 64) * 768 + kt * 64,
                             Wt1l + (size_t)(nt * 64) * 768 + kt * 64, 768, Th, Tl);
    } else if (id < 312) {
        int r = id - 288, kt = r >> 1, nh = r & 1;
        transpose_split_tile(A1 + (size_t)(nh * 768 + kt * 64) * 64, 64,
                             A1th + (size_t)(nh * 64) * 768 + kt * 64,
                             A1tl + (size_t)(nh * 64) * 768 + kt * 64, 768, Th, Tl);
    } else if (id < 504) {
        flat_split_job(feature, fh, fl, (size_t)(id - 312) * 4096 + tid * 16);
    } else if (id < 648) {
        flat_split_job(W0, Wrm0h, Wrm0l, (size_t)(id - 504) * 4096 + tid * 16);
    } else if (id < 792) {
        flat_split_job(W1, Wrm1h, Wrm1l, (size_t)(id - 648) * 4096 + tid * 16);
    } else {
        // bA[layer][c] = sum_k b[k] * A1x[k][c]
        int layer = id - 792;
        const float* bv = layer ? b1 : b0;
        int c = tid & 127, half = tid >> 7;
        float acc = 0.f;
        for (int kk = 0; kk < 384; kk++) {
            int k = half * 384 + kk;
            int row = (c < 64 ? k : 768 + k);
            acc += bv[k] * A1[(size_t)row * 64 + (c & 63)];
        }
        redb[tid] = acc;
        __syncthreads();
        if (tid < 128) bA[layer * 128 + tid] = redb[tid] + redb[tid + 128];
    }
}

// ---------------------------------------------------------------------------
// wa_gemm: WAt[layer][c][r] = sum_k A1x[k][c] * W[r][k]  (c in 128, r in 768)
// A = A1t split [128][768]; B = W row-major split. grid (12, 2, 2).
// ---------------------------------------------------------------------------
__global__ __launch_bounds__(256) void wa_gemm_k(
    const unsigned short* __restrict__ A1th, const unsigned short* __restrict__ A1tl,
    const unsigned short* __restrict__ Wrm0h, const unsigned short* __restrict__ Wrm0l,
    const unsigned short* __restrict__ Wrm1h, const unsigned short* __restrict__ Wrm1l,
    unsigned short* __restrict__ WAth, unsigned short* __restrict__ WAtl)
{
    __shared__ unsigned short smem[4][64][40];
    int bx = blockIdx.x, by = blockIdx.y, layer = blockIdx.z;
    const unsigned short* Bh = layer ? Wrm1h : Wrm0h;
    const unsigned short* Bl = layer ? Wrm1l : Wrm0l;
    int row0 = by * 64, col0 = bx * 64;
    f32x4 acc[2][2] = {};
    mfma_loop(A1th, A1tl, 768, Bh, Bl, 768, 768, row0, col0, acc,
              smem[0], smem[1], smem[2], smem[3]);
    __syncthreads();
    unsigned short* flat = &smem[0][0][0];
    unsigned short (*Hi)[69] = (unsigned short(*)[69])flat;
    unsigned short (*Lo)[69] = (unsigned short(*)[69])(flat + 4416);
    int tid = threadIdx.x, lane = tid & 63, wid = tid >> 6;
    int wm0 = (wid >> 1) * 32, wn0 = (wid & 1) * 32;
    int lm = lane & 15, q = lane >> 4;
#pragma unroll
    for (int mt = 0; mt < 2; mt++)
#pragma unroll
        for (int nt = 0; nt < 2; nt++) {
            int c = wn0 + nt * 16 + lm;
#pragma unroll
            for (int i = 0; i < 4; i++) {
                int r = wm0 + mt * 16 + q * 4 + i;
                unsigned short hv, lv;
                split2(acc[mt][nt][i], hv, lv);
                Hi[r][c] = hv; Lo[r][c] = lv;
            }
        }
    __syncthreads();
    int r = tid >> 2, cq = (tid & 3) * 16;
    bs8 vh0, vh1, vl0, vl1;
#pragma unroll
    for (int e = 0; e < 8; e++) {
        vh0[e] = Hi[r][cq + e];     vh1[e] = Hi[r][cq + 8 + e];
        vl0[e] = Lo[r][cq + e];     vl1[e] = Lo[r][cq + 8 + e];
    }
    size_t ro = (size_t)layer * 98304 + (size_t)(row0 + r) * 768 + col0 + cq;
    *(bs8*)(WAth + ro) = vh0; *(bs8*)(WAth + ro + 8) = vh1;
    *(bs8*)(WAtl + ro) = vl0; *(bs8*)(WAtl + ro + 8) = vl1;
}

// ---------------------------------------------------------------------------
// Fused gemm: grid (14, 16). col-tiles 0-11: h = A@W + bias -> transposed
// split hth/htl (attn B). col-tiles 12-13: s = A@WA -> fp32 (bias in score).
// ---------------------------------------------------------------------------
__global__ __launch_bounds__(256) void gemm_fused_k(
    const unsigned short* __restrict__ Ahg, const unsigned short* __restrict__ Alg,
    const unsigned short* __restrict__ Wth, const unsigned short* __restrict__ Wtl,
    const unsigned short* __restrict__ WAth, const unsigned short* __restrict__ WAtl,
    const float* __restrict__ bias,
    unsigned short* __restrict__ hth, unsigned short* __restrict__ htl,
    float* __restrict__ s)
{
    __shared__ unsigned short smem[4][64][40];
    int bx = blockIdx.x, row0 = blockIdx.y * 64;
    const unsigned short* Bh;
    const unsigned short* Bl;
    int col0;
    if (bx < 12) { Bh = Wth;  Bl = Wtl;  col0 = bx * 64; }
    else         { Bh = WAth; Bl = WAtl; col0 = (bx - 12) * 64; }
    f32x4 acc[2][2] = {};
    mfma_loop(Ahg, Alg, 768, Bh, Bl, 768, 768, row0, col0, acc,
              smem[0], smem[1], smem[2], smem[3]);
    int tid = threadIdx.x, lane = tid & 63, wid = tid >> 6;
    int wm0 = (wid >> 1) * 32, wn0 = (wid & 1) * 32;
    int lm = lane & 15, q = lane >> 4;
    if (bx >= 12) {
        // s-path: fp32 write, no bias (bA added in score_k)
#pragma unroll
        for (int mt = 0; mt < 2; mt++)
#pragma unroll
            for (int nt = 0; nt < 2; nt++) {
                int c = col0 + wn0 + nt * 16 + lm;
#pragma unroll
                for (int i = 0; i < 4; i++) {
                    int r = row0 + wm0 + mt * 16 + q * 4 + i;
                    s[(size_t)r * 128 + c] = acc[mt][nt][i];
                }
            }
        return;
    }
    __syncthreads();
    unsigned short* flat = &smem[0][0][0];
    unsigned short (*Hi)[69] = (unsigned short(*)[69])flat;
    unsigned short (*Lo)[69] = (unsigned short(*)[69])(flat + 4416);
#pragma unroll
    for (int mt = 0; mt < 2; mt++)
#pragma unroll
        for (int nt = 0; nt < 2; nt++) {
            int c = wn0 + nt * 16 + lm;
            float bv = bias[col0 + c];
#pragma unroll
            for (int i = 0; i < 4; i++) {
                int r = wm0 + mt * 16 + q * 4 + i;
                unsigned short hv, lv;
                split2(acc[mt][nt][i] + bv, hv, lv);
                Hi[r][c] = hv; Lo[r][c] = lv;
            }
        }
    __syncthreads();
    // transposed per-batch split out: hth[b][d][k], ld 128
    int d = tid >> 2, kq = (tid & 3) * 16;
    int b = row0 >> 7, kb = row0 & 127;
    bs8 th0, th1, tl0, tl1;
#pragma unroll
    for (int e = 0; e < 8; e++) {
        th0[e] = Hi[kq + e][d];     th1[e] = Hi[kq + 8 + e][d];
        tl0[e] = Lo[kq + e][d];     tl1[e] = Lo[kq + 8 + e][d];
    }
    size_t to = ((size_t)b * 768 + col0 + d) * 128 + kb + kq;
    *(bs8*)(hth + to) = th0; *(bs8*)(hth + to + 8) = th1;
    *(bs8*)(htl + to) = tl0; *(bs8*)(htl + to + 8) = tl1;
}

// ---------------------------------------------------------------------------
// score_k: masked score + exp (no max-shift; |e|<<80 by construction, masked
// entries = 0 exactly). Writes split exp to ph/pl + per-block sum psum[b][32].
// grid (32 i-tiles, 8 b), block 256: 4 rows x 128 cols, 2 elems/thread.
// ---------------------------------------------------------------------------
__global__ __launch_bounds__(256) void score_k(
    const float* __restrict__ s, const int* __restrict__ adj,
    const float* __restrict__ ab1, const float* __restrict__ A2,
    const float* __restrict__ ab2, const float* __restrict__ bA,
    unsigned short* __restrict__ ph, unsigned short* __restrict__ pl,
    float* __restrict__ psum)
{
    __shared__ float st[128][65];
    __shared__ float ss[4][65];
    __shared__ float a2s[64];
    __shared__ float warr[4];
    const int bx = blockIdx.x, b = blockIdx.y, tid = threadIdx.x;
    const int i0 = bx * 4;
    for (int idx = tid; idx < 8192; idx += 256) {
        int j = idx >> 6, h2 = idx & 63;
        st[j][h2] = s[(size_t)(b * 128 + j) * 128 + 64 + h2] + bA[64 + h2];
    }
    {
        int i = tid >> 6, h2 = tid & 63;
        ss[i][h2] = s[(size_t)(b * 128 + i0 + i) * 128 + h2] + bA[h2] + ab1[h2];
    }
    if (tid < 64) a2s[tid] = A2[tid];
    __syncthreads();
    const float ab2v = ab2[0];
    const int rr = tid >> 7;        // 0..1
    const int j = tid & 127;
    const int r0 = rr * 2, r1 = rr * 2 + 1;
    float acc0 = 0.f, acc1 = 0.f;
#pragma unroll 4
    for (int h2 = 0; h2 < 64; h2++) {
        float bb = st[j][h2];
        float cv = a2s[h2];
        acc0 = fmaf(fmaxf(ss[r0][h2] + bb, 0.f), cv, acc0);
        acc1 = fmaf(fmaxf(ss[r1][h2] + bb, 0.f), cv, acc1);
    }
    float e0 = acc0 + ab2v; e0 = (e0 > 0.f) ? e0 : SLOPE_V * e0;
    float e1 = acc1 + ab2v; e1 = (e1 > 0.f) ? e1 : SLOPE_V * e1;
    size_t o0 = (size_t)b * 16384 + (size_t)(i0 + r0) * 128 + j;
    size_t o1 = (size_t)b * 16384 + (size_t)(i0 + r1) * 128 + j;
    float v0 = adj[o0] ? expf(e0) : 0.f;
    float v1 = adj[o1] ? expf(e1) : 0.f;
    unsigned short hv, lv;
    split2(v0, hv, lv); ph[o0] = hv; pl[o0] = lv;
    split2(v1, hv, lv); ph[o1] = hv; pl[o1] = lv;
    float vs = v0 + v1;
#pragma unroll
    for (int o = 32; o > 0; o >>= 1) vs += __shfl_down(vs, o);
    if ((tid & 63) == 0) warr[tid >> 6] = vs;
    __syncthreads();
    if (tid == 0) psum[b * 32 + bx] = warr[0] + warr[1] + warr[2] + warr[3];
}

// ---------------------------------------------------------------------------
// attn: node[b] = (1/sum_b) * P[b] @ h[b]; alpha from psum partials.
// Outputs fp32 node AND split ndh/ndl. grid (12,2,8).
// ---------------------------------------------------------------------------
__global__ __launch_bounds__(256) void attn_mfma_k(
    const unsigned short* __restrict__ ph, const unsigned short* __restrict__ pl,
    const unsigned short* __restrict__ hth, const unsigned short* __restrict__ htl,
    const float* __restrict__ psum, float* __restrict__ node,
    unsigned short* __restrict__ nodeh, unsigned short* __restrict__ nodel)
{
    __shared__ unsigned short smem[4][64][40];
    __shared__ float sred[33];
    int b = blockIdx.z;
    int row0 = blockIdx.y * 64, col0 = blockIdx.x * 64;
    int tid = threadIdx.x;
    if (tid < 32) sred[tid] = psum[b * 32 + tid];
    __syncthreads();
    if (tid == 0) {
        float t = 0.f;
#pragma unroll
        for (int i = 0; i < 32; i++) t += sred[i];
        sred[32] = 1.0f / t;
    }
    __syncthreads();
    float alpha = sred[32];
    f32x4 acc[2][2] = {};
    mfma_loop(ph + (size_t)b * 16384, pl + (size_t)b * 16384, 128,
              hth + (size_t)b * 98304, htl + (size_t)b * 98304, 128, 128,
              row0, col0, acc, smem[0], smem[1], smem[2], smem[3]);
    __syncthreads();
    float* C = node + (size_t)b * 98304;
    unsigned short* flat = &smem[0][0][0];
    unsigned short (*Hi)[69] = (unsigned short(*)[69])flat;
    unsigned short (*Lo)[69] = (unsigned short(*)[69])(flat + 4416);
    int lane = tid & 63, wid = tid >> 6;
    int wm0 = (wid >> 1) * 32, wn0 = (wid & 1) * 32;
    int lm = lane & 15, q = lane >> 4;
#pragma unroll
    for (int mt = 0; mt < 2; mt++)
#pragma unroll
        for (int nt = 0; nt < 2; nt++) {
            int c = wn0 + nt * 16 + lm;
#pragma unroll
            for (int i = 0; i < 4; i++) {
                int r = wm0 + mt * 16 + q * 4 + i;
                float v = acc[mt][nt][i] * alpha;
                C[(size_t)(row0 + r) * 768 + col0 + c] = v;
                unsigned short hv, lv;
                split2(v, hv, lv);
                Hi[r][c] = hv; Lo[r][c] = lv;
            }
        }
    __syncthreads();
    int r = tid >> 2, cq = (tid & 3) * 16;
    bs8 vh0, vh1, vl0, vl1;
#pragma unroll
    for (int e = 0; e < 8; e++) {
        vh0[e] = Hi[r][cq + e];     vh1[e] = Hi[r][cq + 8 + e];
        vl0[e] = Lo[r][cq + e];     vl1[e] = Lo[r][cq + 8 + e];
    }
    size_t ro = (size_t)(b * 128 + row0 + r) * 768 + col0 + cq;
    *(bs8*)(nodeh + ro) = vh0; *(bs8*)(nodeh + ro + 8) = vh1;
    *(bs8*)(nodel + ro) = vl0; *(bs8*)(nodel + ro + 8) = vl1;
}

// ---------------------------------------------------------------------------
// Fused graph-sum + batch-norm. grid 12, block 512.
// ---------------------------------------------------------------------------
__global__ __launch_bounds__(512) void gsum_bnorm_k(
    const float* __restrict__ node, const float* __restrict__ gamma,
    const float* __restrict__ beta, float* __restrict__ out)
{
    __shared__ float gbuf[8][64];
    __shared__ float mean_s[64], inv_s[64];
    int tid = threadIdx.x;
    int bg = tid >> 6, dl = tid & 63;
    int d = blockIdx.x * 64 + dl;
    float v = 0.f;
    for (int i = 0; i < 128; i++)
        v += node[(size_t)(bg * 128 + i) * 768 + d];
    gbuf[bg][dl] = v;
    __syncthreads();
    if (tid < 64) {
        float m = 0.f;
#pragma unroll
        for (int b = 0; b < 8; b++) m += gbuf[b][tid];
        m *= 0.125f;
        float var = 0.f;
#pragma unroll
        for (int b = 0; b < 8; b++) { float t = gbuf[b][tid] - m; var += t * t; }
        var *= 0.125f;
        mean_s[tid] = m;
        inv_s[tid] = 1.0f / sqrtf(var + EPS_V);
    }
    __syncthreads();
    out[bg * 768 + d] = gamma[d] * (v - mean_s[dl]) * inv_s[dl] + beta[d];
}

// ---------------------------------------------------------------------------
extern "C" void kernel_launch(void* const* d_in, const int* in_sizes, int n_in,
                              void* d_out, int out_size, void* d_ws, size_t ws_size,
                              hipStream_t stream)
{
    const float* feature = (const float*)d_in[0];
    // d_in[1] = aspect: unused by the reference
    const int*   adj     = (const int*)d_in[2];
    const float* W0      = (const float*)d_in[3];
    const float* b0      = (const float*)d_in[4];
    const float* W1      = (const float*)d_in[5];
    const float* b1      = (const float*)d_in[6];
    const float* A1      = (const float*)d_in[7];
    const float* ab1     = (const float*)d_in[8];
    const float* A2      = (const float*)d_in[9];
    const float* ab2     = (const float*)d_in[10];
    const float* gamma   = (const float*)d_in[11];
    const float* beta    = (const float*)d_in[12];

    float* ws    = (float*)d_ws;
    float* s     = ws;               // 131072
    float* psum  = ws + 131072;      // 256
    float* bA    = ws + 131328;      // 256
    unsigned short* u = (unsigned short*)(ws + 131584);  // 16B-aligned
    unsigned short* Wt0h  = u;                    // 589824 each
    unsigned short* Wt0l  = Wt0h + 589824;
    unsigned short* Wt1h  = Wt0l + 589824;
    unsigned short* Wt1l  = Wt1h + 589824;
    unsigned short* A1th  = Wt1l + 589824;        // 98304 each
    unsigned short* A1tl  = A1th + 98304;
    unsigned short* Wrm0h = A1tl + 98304;         // 589824 each
    unsigned short* Wrm0l = Wrm0h + 589824;
    unsigned short* Wrm1h = Wrm0l + 589824;
    unsigned short* Wrm1l = Wrm1h + 589824;
    unsigned short* WAth  = Wrm1l + 589824;       // 196608 each (2 layers)
    unsigned short* WAtl  = WAth + 196608;
    unsigned short* fh    = WAtl + 196608;        // 786432 each
    unsigned short* fl    = fh + 786432;
    unsigned short* hth   = fl + 786432;
    unsigned short* htl   = hth + 786432;
    unsigned short* ndh   = htl + 786432;
    unsigned short* ndl   = ndh + 786432;
    unsigned short* ph    = ndl + 786432;         // 131072 each
    unsigned short* pl    = ph + 131072;

    float* out       = (float*)d_out;
    float* graph_out = out;          // (8,768)
    float* node_out  = out + 6144;   // (8,128,768)

    prep_k<<<794, 256, 0, stream>>>(W0, W1, A1, feature, b0, b1,
                                    Wt0h, Wt0l, Wt1h, Wt1l, A1th, A1tl,
                                    fh, fl, Wrm0h, Wrm0l, Wrm1h, Wrm1l, bA);
    wa_gemm_k<<<dim3(12, 2, 2), 256, 0, stream>>>(A1th, A1tl,
                                                  Wrm0h, Wrm0l, Wrm1h, Wrm1l,
                                                  WAth, WAtl);

    for (int layer = 0; layer < 2; layer++) {
        const unsigned short* Wth = layer ? Wt1h : Wt0h;
        const unsigned short* Wtl = layer ? Wt1l : Wt0l;
        const float* bb = layer ? b1 : b0;
        const unsigned short* Ahg = layer ? ndh : fh;
        const unsigned short* Alg = layer ? ndl : fl;
        gemm_fused_k<<<dim3(14, 16), 256, 0, stream>>>(
            Ahg, Alg, Wth, Wtl, WAth + (size_t)layer * 98304,
            WAtl + (size_t)layer * 98304, bb, hth, htl, s);
        score_k<<<dim3(32, 8), 256, 0, stream>>>(s, adj, ab1, A2, ab2,
                                                 bA + layer * 128, ph, pl, psum);
        attn_mfma_k<<<dim3(12, 2, 8), 256, 0, stream>>>(ph, pl, hth, htl, psum,
                                                        node_out, ndh, ndl);
    }
    gsum_bnorm_k<<<12, 512, 0, stream>>>(node_out, gamma, beta, graph_out);
}